// Round 1
// baseline (309.520 us; speedup 1.0000x reference)
//
#include <hip/hip_runtime.h>

#define NN 50000
#define NE 1600000
#define DD 64
#define ELLW 72          // fixed records per node row: P(deg>72|Poisson(32))~5e-10
#define EBLK 1563        // edge-scatter blocks: 1563*256 >= NE/4 = 400000 int4-groups

typedef __attribute__((ext_vector_type(8))) short bf16x8;   // 8 bf16 = 4 VGPR
typedef __attribute__((ext_vector_type(4))) float f32x4;
typedef __attribute__((ext_vector_type(2))) float f32x2;

static __device__ __forceinline__ unsigned short f2bf(float f) {
    unsigned int u = __float_as_uint(f);
    unsigned int r = (u + 0x7FFFu + ((u >> 16) & 1u)) >> 16;   // RNE
    return (unsigned short)r;
}
static __device__ __forceinline__ float bf2f(unsigned short h) {
    return __uint_as_float((unsigned int)h << 16);
}
// pack 4 fp32 -> 4 x fp8-e4m3 (OCP, HW cvt)
static __device__ __forceinline__ unsigned int pk_fp8x4(float a, float b, float c, float d) {
    unsigned int p = __builtin_amdgcn_cvt_pk_fp8_f32(a, b, 0u, false);
    p = __builtin_amdgcn_cvt_pk_fp8_f32(c, d, p, true);
    return p;
}

// ---------------------------------------------------------------------------
// R16: direct-atomic ELL scatter replaces the whole binning pipeline
// (prep_bin LDS buckets + build_ell). Per edge: pos = atomicAdd(cnt[src]),
// record -> csr[src*72+pos]. 1.6M L2 atomics over 50K addresses (avg 32
// collisions/address across the whole kernel) — latency hidden by ~400K
// concurrent threads. Record: dst(16) | w_bf16<<16. cnt[] ends at TRUE
// degree (atomic count), same divisor semantics as before. Rows are NOT
// zero-padded; fused_layer masks the remainder instead.
// Blocks 0..EBLK-1: edge scatter. Blocks EBLK..EBLK+3124: x->bf16+fp8 cast.
// Blocks EBLK+3125..EBLK+3140: W->bf16 cast.
// cnt[] is zeroed by hipMemsetAsync before this kernel.
// ---------------------------------------------------------------------------
__global__ __launch_bounds__(256) void prep_scatter(
    const int* __restrict__ ei, const float* __restrict__ ew,
    int* __restrict__ cnt, unsigned int* __restrict__ csr,
    const float* __restrict__ x, ushort* __restrict__ xb,
    unsigned int* __restrict__ xf8,
    const float* __restrict__ W1, const float* __restrict__ W2,
    ushort* __restrict__ W1b, ushort* __restrict__ W2b)
{
    int tid = threadIdx.x;
    int blk = blockIdx.x;

    if (blk >= EBLK) {
        int pb = blk - EBLK;
        if (pb < 3125) {                   // 3125*256 = 800000 = NN*DD/4
            int i = pb * 256 + tid;
            float4 v = ((const float4*)x)[i];
            ushort4 o;
            o.x = f2bf(v.x); o.y = f2bf(v.y); o.z = f2bf(v.z); o.w = f2bf(v.w);
            ((ushort4*)xb)[i] = o;
            xf8[i] = pk_fp8x4(v.x, v.y, v.z, v.w);
        } else {                           // 16*256 = 4096 float4 groups
            int i = (pb - 3125) * 256 + tid;
            const float* src = (i < 2048) ? W1 : W2;
            ushort* dst = (i < 2048) ? W1b : W2b;
            int j = i & 2047;
            float4 v = ((const float4*)src)[j];
            ushort4 o;
            o.x = f2bf(v.x); o.y = f2bf(v.y); o.z = f2bf(v.z); o.w = f2bf(v.w);
            ((ushort4*)dst)[j] = o;
        }
        return;
    }

    // edge scatter: one int4-group (4 edges) per thread
    int idx = blk * 256 + tid;
    if (idx >= NE / 4) return;
    const int4*   s4 = (const int4*)ei;            // src words
    const int4*   d4 = ((const int4*)ei) + NE / 4; // dst words
    const float4* w4 = (const float4*)ew;
    int4 sv = s4[idx];
    int4 dv = d4[idx];
    float4 wv = w4[idx];
#pragma unroll
    for (int k = 0; k < 4; ++k) {
        int s   = (k == 0) ? sv.x : (k == 1) ? sv.y : (k == 2) ? sv.z : sv.w;
        int d   = (k == 0) ? dv.x : (k == 1) ? dv.y : (k == 2) ? dv.z : dv.w;
        float w = (k == 0) ? wv.x : (k == 1) ? wv.y : (k == 2) ? wv.z : wv.w;
        int pos = atomicAdd(&cnt[s], 1);
        if (pos < ELLW)
            csr[(size_t)s * ELLW + pos] =
                (unsigned int)d | ((unsigned int)f2bf(w) << 16);
    }
}

// ---------------------------------------------------------------------------
// FUSED layer (R14-proven): block = 1024 thr = 16 waves = 16 nodes.
// Phase 1: wave w aggregates node base+w over the fp8 table (one 256B gather
// = 4 rows; groups combined via shfl_xor) -> LDS tiles (stride 72 ushorts).
// Phase 2: waves 0-3 = one 16-col output tile each, 4 MFMAs (R7 layouts).
// R16: rows are unpadded; main loop runs to the exact multiple of 16, the
// remainder masks invalid records to 0 (f8 row 0 gather x weight 0 = 0 —
// never multiplies garbage, so no NaN path).
// ---------------------------------------------------------------------------
__global__ __launch_bounds__(1024) void fused_layer(
    const ushort* __restrict__ Xb,          // self features bf16 [NN][64]
    const unsigned int* __restrict__ f8,    // gather table fp8, 16 uints/row
    const int* __restrict__ cnt, const unsigned int* __restrict__ csr,
    const ushort* __restrict__ Wb, const float* __restrict__ bias,
    float* __restrict__ out, ushort* __restrict__ outb,
    unsigned char* __restrict__ outf8)
{
    __shared__ ushort xL[16][72];
    __shared__ ushort aggL[16][72];
    int tid = threadIdx.x;
    int wave = tid >> 6, lane = tid & 63;
    int g = lane >> 4, l16 = lane & 15;
    int base = blockIdx.x * 16;
    int node = base + wave;                 // always < NN (NN = 3125*16)

    // stage self row (independent load, issued early)
    if (lane < 16)
        *(ushort4*)&xL[wave][l16 * 4] =
            *(const ushort4*)&Xb[(size_t)node * DD + l16 * 4];

    // ---- phase 1: aggregate ----
    int nd = cnt[node];
    int n = nd < ELLW ? nd : ELLW;
    const unsigned int* __restrict__ rp = csr + (size_t)node * ELLW;
    float a0 = 0.f, a1 = 0.f, a2 = 0.f, a3 = 0.f;

    int i = 0;
    for (; i + 16 <= n; i += 16) {
        uint4 r = *(const uint4*)(rp + i + g * 4);
        unsigned int v0 = f8[(r.x & 0xFFFF) * 16 + l16];
        unsigned int v1 = f8[(r.y & 0xFFFF) * 16 + l16];
        unsigned int v2 = f8[(r.z & 0xFFFF) * 16 + l16];
        unsigned int v3 = f8[(r.w & 0xFFFF) * 16 + l16];
        float w0 = bf2f((unsigned short)(r.x >> 16));
        float w1 = bf2f((unsigned short)(r.y >> 16));
        float w2 = bf2f((unsigned short)(r.z >> 16));
        float w3 = bf2f((unsigned short)(r.w >> 16));
        f32x2 lo, hi;
        lo = __builtin_amdgcn_cvt_pk_f32_fp8(v0, false);
        hi = __builtin_amdgcn_cvt_pk_f32_fp8(v0, true);
        a0 += w0 * lo.x; a1 += w0 * lo.y; a2 += w0 * hi.x; a3 += w0 * hi.y;
        lo = __builtin_amdgcn_cvt_pk_f32_fp8(v1, false);
        hi = __builtin_amdgcn_cvt_pk_f32_fp8(v1, true);
        a0 += w1 * lo.x; a1 += w1 * lo.y; a2 += w1 * hi.x; a3 += w1 * hi.y;
        lo = __builtin_amdgcn_cvt_pk_f32_fp8(v2, false);
        hi = __builtin_amdgcn_cvt_pk_f32_fp8(v2, true);
        a0 += w2 * lo.x; a1 += w2 * lo.y; a2 += w2 * hi.x; a3 += w2 * hi.y;
        lo = __builtin_amdgcn_cvt_pk_f32_fp8(v3, false);
        hi = __builtin_amdgcn_cvt_pk_f32_fp8(v3, true);
        a0 += w3 * lo.x; a1 += w3 * lo.y; a2 += w3 * hi.x; a3 += w3 * hi.y;
    }
    for (; i < n; i += 4) {   // remainder: 4 records, one per group (masked)
        uint4 r = *(const uint4*)(rp + i);
        unsigned int e = (g == 0) ? r.x : (g == 1) ? r.y : (g == 2) ? r.z : r.w;
        if (i + g >= n) e = 0u;   // row-0 gather x weight 0 = exact 0
        unsigned int v = f8[(e & 0xFFFF) * 16 + l16];
        float w = bf2f((unsigned short)(e >> 16));
        f32x2 lo = __builtin_amdgcn_cvt_pk_f32_fp8(v, false);
        f32x2 hi = __builtin_amdgcn_cvt_pk_f32_fp8(v, true);
        a0 += w * lo.x; a1 += w * lo.y; a2 += w * hi.x; a3 += w * hi.y;
    }

    a0 += __shfl_xor(a0, 16); a0 += __shfl_xor(a0, 32);
    a1 += __shfl_xor(a1, 16); a1 += __shfl_xor(a1, 32);
    a2 += __shfl_xor(a2, 16); a2 += __shfl_xor(a2, 32);
    a3 += __shfl_xor(a3, 16); a3 += __shfl_xor(a3, 32);

    if (lane < 16) {
        float dm = (float)(nd > 1 ? nd : 1);
        ushort4 o;
        o.x = f2bf(a0 / dm); o.y = f2bf(a1 / dm);
        o.z = f2bf(a2 / dm); o.w = f2bf(a3 / dm);
        *(ushort4*)&aggL[wave][l16 * 4] = o;
    }
    __syncthreads();

    // ---- phase 2: GEMM (waves 0-3; wave = col tile) ----
    if (wave < 4) {
        f32x4 acc = (f32x4){0.f, 0.f, 0.f, 0.f};
#pragma unroll
        for (int ki = 0; ki < 4; ++ki) {
            const ushort* ap = (ki < 2) ? &xL[l16][ki * 32 + g * 8]
                                        : &aggL[l16][(ki - 2) * 32 + g * 8];
            bf16x8 af = *(const bf16x8*)ap;
            bf16x8 bfrag = *(const bf16x8*)&Wb[(size_t)(wave * 16 + l16) * 128 + ki * 32 + g * 8];
            acc = __builtin_amdgcn_mfma_f32_16x16x32_bf16(af, bfrag, acc, 0, 0, 0);
        }
        int col = wave * 16 + l16;
        float bv = bias[col];
#pragma unroll
        for (int r = 0; r < 4; ++r) {
            int grow = base + g * 4 + r;   // C/D: col=lane&15, row=quad*4+reg
            float v = fmaxf(acc[r] + bv, 0.f);
            if (out)  out[(size_t)grow * DD + col] = v;
            if (outb) outb[(size_t)grow * DD + col] = f2bf(v);
            if (outf8) {
                unsigned int p = __builtin_amdgcn_cvt_pk_fp8_f32(v, v, 0u, false);
                outf8[(size_t)grow * DD + col] = (unsigned char)(p & 0xFFu);
            }
        }
    }
}

// ---------------------------------------------------------------------------
extern "C" void kernel_launch(void* const* d_in, const int* in_sizes, int n_in,
                              void* d_out, int out_size, void* d_ws, size_t ws_size,
                              hipStream_t stream)
{
    const float* x  = (const float*)d_in[0];
    const int*   ei = (const int*)d_in[1];
    const float* ew = (const float*)d_in[2];
    const float* W1 = (const float*)d_in[3];
    const float* b1 = (const float*)d_in[4];
    const float* W2 = (const float*)d_in[5];
    const float* b2 = (const float*)d_in[6];
    float* out = (float*)d_out;

    // workspace layout, ~33.9 MB (16B-aligned offsets)
    char* ws = (char*)d_ws;
    int*          cnt  = (int*)ws;                        //    200,704 B
    unsigned int* csr  = (unsigned int*)(ws + 200704);    // 14,400,000 B (ELL 72/node)
    ushort*       xb   = (ushort*)(ws + 14600704);        //  6,400,000 B
    ushort*       h1b  = (ushort*)(ws + 21000704);        //  6,400,000 B
    ushort*       W1b  = (ushort*)(ws + 27400704);        //     16,384 B
    ushort*       W2b  = (ushort*)(ws + 27417088);        //     16,384 B
    unsigned int* xf8  = (unsigned int*)(ws + 27433472);  //  3,200,000 B
    unsigned char* h1f8 = (unsigned char*)(ws + 30633472);//  3,200,000 B

    hipMemsetAsync(cnt, 0, 200704, stream);

    // fused: edge scatter (direct-atomic ELL) + x/W casts
    prep_scatter<<<EBLK + 3141, 256, 0, stream>>>(ei, ew, cnt, csr,
                                                  x, xb, xf8, W1, W2, W1b, W2b);

    // layer 1: gather fp8(x), self bf16(x) -> h1b + h1f8
    fused_layer<<<NN / 16, 1024, 0, stream>>>(xb, xf8, cnt, csr, W1b, b1,
                                              nullptr, h1b, h1f8);
    // layer 2: gather fp8(h1), self bf16(h1) -> out
    fused_layer<<<NN / 16, 1024, 0, stream>>>(h1b, (const unsigned int*)h1f8,
                                              cnt, csr, W2b, b2, out, nullptr, nullptr);
}

// Round 2
// 174.246 us; speedup vs baseline: 1.7763x; 1.7763x over previous
//
#include <hip/hip_runtime.h>

#define NN 50000
#define NE 1600000
#define DD 64
#define NPB 196          // nodes per bucket
#define NBKT 256         // buckets (NPB*NBKT = 50176 >= NN)
#define CHUNK 2500       // edges per bin block (640 blocks * 2500 = NE)
#define NBLK 640
#define SLOT 24          // LDS records per bucket: lambda=9.77, +4.5 sigma
#define SSTR 25          // LDS stride pad (R12-proven)
#define S1CAP 1024       // per-(bucket,shard) region: lambda=781, +8.7 sigma
#define SPCAP 512        // per-bucket global spill region
#define ELLW 80          // fixed records per node row (pad-to-16 capable); P(deg>80)~1e-12

typedef __attribute__((ext_vector_type(8))) short bf16x8;   // 8 bf16 = 4 VGPR
typedef __attribute__((ext_vector_type(4))) float f32x4;
typedef __attribute__((ext_vector_type(2))) float f32x2;

static __device__ __forceinline__ unsigned short f2bf(float f) {
    unsigned int u = __float_as_uint(f);
    unsigned int r = (u + 0x7FFFu + ((u >> 16) & 1u)) >> 16;   // RNE
    return (unsigned short)r;
}
static __device__ __forceinline__ float bf2f(unsigned short h) {
    return __uint_as_float((unsigned int)h << 16);
}
// pack 4 fp32 -> 4 x fp8-e4m3 (OCP, HW cvt)
static __device__ __forceinline__ unsigned int pk_fp8x4(float a, float b, float c, float d) {
    unsigned int p = __builtin_amdgcn_cvt_pk_fp8_f32(a, b, 0u, false);
    p = __builtin_amdgcn_cvt_pk_fp8_f32(c, d, p, true);
    return p;
}

// ---------------------------------------------------------------------------
// R15-proven FUSED prep + binning (restored after R16's global-atomic scatter
// regressed: memory-side atomics = 64B write-through each, 106 MB WRITE_SIZE,
// 157 us). Blocks 0..639: LDS-staged edge binning. Blocks 640..3764: x cast.
// Blocks 3765..3780: W cast. gcur/gspillc zeroed by hipMemsetAsync before.
// Record: .x = dst(16) | w_bf16<<16, .y = node-within-bucket.
// ---------------------------------------------------------------------------
__global__ __launch_bounds__(256) void prep_bin(
    const int* __restrict__ ei, const float* __restrict__ ew,
    int* __restrict__ gcur, int* __restrict__ gspillc,
    int2* __restrict__ buf1, int2* __restrict__ spill,
    const float* __restrict__ x, ushort* __restrict__ xb,
    unsigned int* __restrict__ xf8,
    const float* __restrict__ W1, const float* __restrict__ W2,
    ushort* __restrict__ W1b, ushort* __restrict__ W2b)
{
    __shared__ int2 slot[NBKT * SSTR];   // 50 KB
    __shared__ int  lcnt[NBKT];
    __shared__ int  lbase[NBKT];
    int tid = threadIdx.x;
    int blk = blockIdx.x;

    if (blk >= NBLK) {
        int pb = blk - NBLK;
        if (pb < 3125) {                   // 3125*256 = 800000 = NN*DD/4
            int i = pb * 256 + tid;
            float4 v = ((const float4*)x)[i];
            ushort4 o;
            o.x = f2bf(v.x); o.y = f2bf(v.y); o.z = f2bf(v.z); o.w = f2bf(v.w);
            ((ushort4*)xb)[i] = o;
            xf8[i] = pk_fp8x4(v.x, v.y, v.z, v.w);
        } else {                           // 16*256 = 4096 float4 groups
            int i = (pb - 3125) * 256 + tid;
            const float* src = (i < 2048) ? W1 : W2;
            ushort* dst = (i < 2048) ? W1b : W2b;
            int j = i & 2047;
            float4 v = ((const float4*)src)[j];
            ushort4 o;
            o.x = f2bf(v.x); o.y = f2bf(v.y); o.z = f2bf(v.z); o.w = f2bf(v.w);
            ((ushort4*)dst)[j] = o;
        }
        return;
    }

    int shard = blk & 7;
    for (int b = tid; b < NBKT; b += 256) lcnt[b] = 0;
    __syncthreads();

    // 4-wide edge loads: CHUNK/4 = 625 int4-groups per block
    int g0 = blk * (CHUNK / 4);            // int4-group base
    const int4*   s4 = (const int4*)ei;            // src words
    const int4*   d4 = ((const int4*)ei) + NE / 4; // dst words
    const float4* w4 = (const float4*)ew;
    for (int it = 0; it < 3; ++it) {
        int idx = it * 256 + tid;
        if (idx >= CHUNK / 4) break;
        int4 sv = s4[g0 + idx];
        int4 dv = d4[g0 + idx];
        float4 wv = w4[g0 + idx];
#pragma unroll
        for (int k = 0; k < 4; ++k) {
            int s = (k == 0) ? sv.x : (k == 1) ? sv.y : (k == 2) ? sv.z : sv.w;
            int d = (k == 0) ? dv.x : (k == 1) ? dv.y : (k == 2) ? dv.z : dv.w;
            float w = (k == 0) ? wv.x : (k == 1) ? wv.y : (k == 2) ? wv.z : wv.w;
            int bkt = s / NPB;
            int sloc = s - bkt * NPB;
            int2 rec = make_int2(d | ((int)f2bf(w) << 16), sloc);
            int pos = atomicAdd(&lcnt[bkt], 1);
            if (pos < SLOT) {
                slot[bkt * SSTR + pos] = rec;
            } else {
                int sp = atomicAdd(&gspillc[bkt], 1);
                if (sp < SPCAP) spill[bkt * SPCAP + sp] = rec;
            }
        }
    }
    __syncthreads();

    // one global reservation per (block,bucket); tid==bucket (256==NBKT)
    {
        int b = tid;
        int n = lcnt[b]; if (n > SLOT) n = SLOT;
        lcnt[b] = n;
        lbase[b] = (n > 0) ? atomicAdd(&gcur[b * 8 + shard], n) : 0;
    }
    __syncthreads();

    // register+shfl flush: wave w owns buckets [w*64, w*64+64) (R10-proven)
    int wave = tid >> 6, lane = tid & 63;
    int b0 = wave * 64;
    int vcnt = lcnt[b0 + lane];
    int vbase = lbase[b0 + lane];
#pragma unroll 8
    for (int j = 0; j < 64; ++j) {
        int n = __shfl(vcnt, j);
        int base = __shfl(vbase, j);
        int b = b0 + j;
        if (lane < n) {
            int2 rec = slot[b * SSTR + lane];
            int p = base + lane;
            if (p < S1CAP) {
                buf1[((size_t)b * 8 + shard) * S1CAP + p] = rec;
            } else {
                int sp = atomicAdd(&gspillc[b], 1);
                if (sp < SPCAP) spill[b * SPCAP + sp] = rec;
            }
        }
    }
}

// ---------------------------------------------------------------------------
// Single-pass ELL build (R15-proven). One block per bucket; LDS cursor per
// node; fixed 80-record rows at csr[node*80]. cnt[node] = TRUE degree.
// R17: rows zero-padded deg..ceil16(deg) so fused_layer's aggregate loop is
// a single uniform 16-step loop (no remainder path at all).
// ---------------------------------------------------------------------------
__global__ __launch_bounds__(1024) void build_ell(
    const int* __restrict__ gcur, const int2* __restrict__ buf1,
    const int* __restrict__ gspillc, const int2* __restrict__ spill,
    unsigned int* __restrict__ csr, int* __restrict__ cnt)
{
    __shared__ int cur[NPB];
    int tid = threadIdx.x, bkt = blockIdx.x;

    if (tid < NPB) cur[tid] = 0;
    __syncthreads();

    for (int sh = 0; sh < 9; ++sh) {
        int n; const int2* rp;
        if (sh < 8) {
            n = gcur[bkt * 8 + sh]; if (n > S1CAP) n = S1CAP;
            rp = buf1 + ((size_t)bkt * 8 + sh) * S1CAP;
        } else {
            n = gspillc[bkt]; if (n > SPCAP) n = SPCAP;
            rp = spill + (size_t)bkt * SPCAP;
        }
        for (int i = tid; i < n; i += 1024) {
            int2 r = rp[i];
            int pos = atomicAdd(&cur[r.y], 1);
            if (pos < ELLW)
                csr[((size_t)(bkt * NPB + r.y)) * ELLW + pos] = (unsigned int)r.x;
        }
    }
    __syncthreads();

    if (tid < NPB) {
        int node = bkt * NPB + tid;
        if (node < NN) {
            int deg = cur[tid];
            cnt[node] = deg;
            int c = deg < ELLW ? deg : ELLW;
            int c16 = (c + 15) & ~15;          // <= 80 always
            for (int p = c; p < c16; ++p)
                csr[(size_t)node * ELLW + p] = 0u;
        }
    }
}

// ---------------------------------------------------------------------------
// R17 FUSED layer: block = 512 thr = 8 waves = 16 nodes (2 per wave,
// interleaved). Rationale (R0 counters): 46 us with VALUBusy 33%, occupancy
// 59%, HBM 10% = latency-bound short dependent chains. Two independent
// gather chains per wave double outstanding loads; 512-thr blocks pack
// 4/CU (vs 2/CU at 1024) and halve barrier scope; phase 2 idles 4/8 waves
// instead of 12/16. Rows are pre-padded to ceil16 -> single uniform loop.
// Phase 2 unchanged (R7 layouts): waves 0-3 = one 16-col tile, 4 MFMAs.
// ---------------------------------------------------------------------------
__global__ __launch_bounds__(512) void fused_layer(
    const ushort* __restrict__ Xb,          // self features bf16 [NN][64]
    const unsigned int* __restrict__ f8,    // gather table fp8, 16 uints/row
    const int* __restrict__ cnt, const unsigned int* __restrict__ csr,
    const ushort* __restrict__ Wb, const float* __restrict__ bias,
    float* __restrict__ out, ushort* __restrict__ outb,
    unsigned char* __restrict__ outf8)
{
    __shared__ ushort xL[16][72];
    __shared__ ushort aggL[16][72];
    int tid = threadIdx.x;
    int wave = tid >> 6, lane = tid & 63;   // wave in 0..7
    int g = lane >> 4, l16 = lane & 15;
    int base = blockIdx.x * 16;
    int nodeA = base + wave;                // rows 0..7 of the block tile
    int nodeB = base + wave + 8;            // rows 8..15

    // stage self rows (independent loads, issued early)
    if (lane < 16) {
        *(ushort4*)&xL[wave][l16 * 4] =
            *(const ushort4*)&Xb[(size_t)nodeA * DD + l16 * 4];
        *(ushort4*)&xL[wave + 8][l16 * 4] =
            *(const ushort4*)&Xb[(size_t)nodeB * DD + l16 * 4];
    }

    // ---- phase 1: aggregate two nodes per wave, interleaved ----
    int ndA = cnt[nodeA], ndB = cnt[nodeB];
    int nA = ndA < ELLW ? ndA : ELLW;
    int nB = ndB < ELLW ? ndB : ELLW;
    int nA16 = (nA + 15) & ~15;             // rows zero-padded to here
    int nB16 = (nB + 15) & ~15;
    int imax = nA16 > nB16 ? nA16 : nB16;
    const unsigned int* __restrict__ rpA = csr + (size_t)nodeA * ELLW;
    const unsigned int* __restrict__ rpB = csr + (size_t)nodeB * ELLW;
    float aA0 = 0.f, aA1 = 0.f, aA2 = 0.f, aA3 = 0.f;
    float aB0 = 0.f, aB1 = 0.f, aB2 = 0.f, aB3 = 0.f;

    for (int i = 0; i < imax; i += 16) {
        // issue both ELL row reads first (independent)
        uint4 rA, rB;
        bool doA = i < nA16, doB = i < nB16;
        if (doA) rA = *(const uint4*)(rpA + i + g * 4);
        if (doB) rB = *(const uint4*)(rpB + i + g * 4);
        if (doA) {
            unsigned int v0 = f8[(rA.x & 0xFFFF) * 16 + l16];
            unsigned int v1 = f8[(rA.y & 0xFFFF) * 16 + l16];
            unsigned int v2 = f8[(rA.z & 0xFFFF) * 16 + l16];
            unsigned int v3 = f8[(rA.w & 0xFFFF) * 16 + l16];
            float w0 = bf2f((unsigned short)(rA.x >> 16));
            float w1 = bf2f((unsigned short)(rA.y >> 16));
            float w2 = bf2f((unsigned short)(rA.z >> 16));
            float w3 = bf2f((unsigned short)(rA.w >> 16));
            f32x2 lo, hi;
            lo = __builtin_amdgcn_cvt_pk_f32_fp8(v0, false);
            hi = __builtin_amdgcn_cvt_pk_f32_fp8(v0, true);
            aA0 += w0 * lo.x; aA1 += w0 * lo.y; aA2 += w0 * hi.x; aA3 += w0 * hi.y;
            lo = __builtin_amdgcn_cvt_pk_f32_fp8(v1, false);
            hi = __builtin_amdgcn_cvt_pk_f32_fp8(v1, true);
            aA0 += w1 * lo.x; aA1 += w1 * lo.y; aA2 += w1 * hi.x; aA3 += w1 * hi.y;
            lo = __builtin_amdgcn_cvt_pk_f32_fp8(v2, false);
            hi = __builtin_amdgcn_cvt_pk_f32_fp8(v2, true);
            aA0 += w2 * lo.x; aA1 += w2 * lo.y; aA2 += w2 * hi.x; aA3 += w2 * hi.y;
            lo = __builtin_amdgcn_cvt_pk_f32_fp8(v3, false);
            hi = __builtin_amdgcn_cvt_pk_f32_fp8(v3, true);
            aA0 += w3 * lo.x; aA1 += w3 * lo.y; aA2 += w3 * hi.x; aA3 += w3 * hi.y;
        }
        if (doB) {
            unsigned int v0 = f8[(rB.x & 0xFFFF) * 16 + l16];
            unsigned int v1 = f8[(rB.y & 0xFFFF) * 16 + l16];
            unsigned int v2 = f8[(rB.z & 0xFFFF) * 16 + l16];
            unsigned int v3 = f8[(rB.w & 0xFFFF) * 16 + l16];
            float w0 = bf2f((unsigned short)(rB.x >> 16));
            float w1 = bf2f((unsigned short)(rB.y >> 16));
            float w2 = bf2f((unsigned short)(rB.z >> 16));
            float w3 = bf2f((unsigned short)(rB.w >> 16));
            f32x2 lo, hi;
            lo = __builtin_amdgcn_cvt_pk_f32_fp8(v0, false);
            hi = __builtin_amdgcn_cvt_pk_f32_fp8(v0, true);
            aB0 += w0 * lo.x; aB1 += w0 * lo.y; aB2 += w0 * hi.x; aB3 += w0 * hi.y;
            lo = __builtin_amdgcn_cvt_pk_f32_fp8(v1, false);
            hi = __builtin_amdgcn_cvt_pk_f32_fp8(v1, true);
            aB0 += w1 * lo.x; aB1 += w1 * lo.y; aB2 += w1 * hi.x; aB3 += w1 * hi.y;
            lo = __builtin_amdgcn_cvt_pk_f32_fp8(v2, false);
            hi = __builtin_amdgcn_cvt_pk_f32_fp8(v2, true);
            aB0 += w2 * lo.x; aB1 += w2 * lo.y; aB2 += w2 * hi.x; aB3 += w2 * hi.y;
            lo = __builtin_amdgcn_cvt_pk_f32_fp8(v3, false);
            hi = __builtin_amdgcn_cvt_pk_f32_fp8(v3, true);
            aB0 += w3 * lo.x; aB1 += w3 * lo.y; aB2 += w3 * hi.x; aB3 += w3 * hi.y;
        }
    }

    aA0 += __shfl_xor(aA0, 16); aA0 += __shfl_xor(aA0, 32);
    aA1 += __shfl_xor(aA1, 16); aA1 += __shfl_xor(aA1, 32);
    aA2 += __shfl_xor(aA2, 16); aA2 += __shfl_xor(aA2, 32);
    aA3 += __shfl_xor(aA3, 16); aA3 += __shfl_xor(aA3, 32);
    aB0 += __shfl_xor(aB0, 16); aB0 += __shfl_xor(aB0, 32);
    aB1 += __shfl_xor(aB1, 16); aB1 += __shfl_xor(aB1, 32);
    aB2 += __shfl_xor(aB2, 16); aB2 += __shfl_xor(aB2, 32);
    aB3 += __shfl_xor(aB3, 16); aB3 += __shfl_xor(aB3, 32);

    if (lane < 16) {
        float dmA = (float)(ndA > 1 ? ndA : 1);
        float dmB = (float)(ndB > 1 ? ndB : 1);
        ushort4 oA, oB;
        oA.x = f2bf(aA0 / dmA); oA.y = f2bf(aA1 / dmA);
        oA.z = f2bf(aA2 / dmA); oA.w = f2bf(aA3 / dmA);
        oB.x = f2bf(aB0 / dmB); oB.y = f2bf(aB1 / dmB);
        oB.z = f2bf(aB2 / dmB); oB.w = f2bf(aB3 / dmB);
        *(ushort4*)&aggL[wave][l16 * 4] = oA;
        *(ushort4*)&aggL[wave + 8][l16 * 4] = oB;
    }
    __syncthreads();

    // ---- phase 2: GEMM (waves 0-3; wave = col tile) ----
    if (wave < 4) {
        f32x4 acc = (f32x4){0.f, 0.f, 0.f, 0.f};
#pragma unroll
        for (int ki = 0; ki < 4; ++ki) {
            const ushort* ap = (ki < 2) ? &xL[l16][ki * 32 + g * 8]
                                        : &aggL[l16][(ki - 2) * 32 + g * 8];
            bf16x8 af = *(const bf16x8*)ap;
            bf16x8 bfrag = *(const bf16x8*)&Wb[(size_t)(wave * 16 + l16) * 128 + ki * 32 + g * 8];
            acc = __builtin_amdgcn_mfma_f32_16x16x32_bf16(af, bfrag, acc, 0, 0, 0);
        }
        int col = wave * 16 + l16;
        float bv = bias[col];
#pragma unroll
        for (int r = 0; r < 4; ++r) {
            int grow = base + g * 4 + r;   // C/D: col=lane&15, row=quad*4+reg
            float v = fmaxf(acc[r] + bv, 0.f);
            if (out)  out[(size_t)grow * DD + col] = v;
            if (outb) outb[(size_t)grow * DD + col] = f2bf(v);
            if (outf8) {
                unsigned int p = __builtin_amdgcn_cvt_pk_fp8_f32(v, v, 0u, false);
                outf8[(size_t)grow * DD + col] = (unsigned char)(p & 0xFFu);
            }
        }
    }
}

// ---------------------------------------------------------------------------
extern "C" void kernel_launch(void* const* d_in, const int* in_sizes, int n_in,
                              void* d_out, int out_size, void* d_ws, size_t ws_size,
                              hipStream_t stream)
{
    const float* x  = (const float*)d_in[0];
    const int*   ei = (const int*)d_in[1];
    const float* ew = (const float*)d_in[2];
    const float* W1 = (const float*)d_in[3];
    const float* b1 = (const float*)d_in[4];
    const float* W2 = (const float*)d_in[5];
    const float* b2 = (const float*)d_in[6];
    float* out = (float*)d_out;

    // workspace layout, ~53.3 MB (16B-aligned offsets)
    char* ws = (char*)d_ws;
    int*          gcur    = (int*)ws;                          //      8,192 B
    int*          gspillc = (int*)(ws + 8192);                 //      1,024 B
    int2*         buf1    = (int2*)(ws + 16384);               // 16,777,216 B
    int2*         spill   = (int2*)(ws + 16793600);            //  1,048,576 B
    unsigned int* csr     = (unsigned int*)(ws + 17842176);    // 16,056,320 B (ELL 80/node)
    int*          cnt     = (int*)(ws + 33898496);             //    200,704 B
    ushort*       xb      = (ushort*)(ws + 34099200);          //  6,400,000 B
    ushort*       h1b     = (ushort*)(ws + 40499200);          //  6,400,000 B
    ushort*       W1b     = (ushort*)(ws + 46899200);          //     16,384 B
    ushort*       W2b     = (ushort*)(ws + 46915584);          //     16,384 B
    unsigned int* xf8     = (unsigned int*)(ws + 46931968);    //  3,200,000 B
    unsigned char* h1f8   = (unsigned char*)(ws + 50131968);   //  3,200,000 B

    hipMemsetAsync(gcur, 0, 9216, stream);   // gcur + gspillc

    prep_bin<<<NBLK + 3141, 256, 0, stream>>>(ei, ew, gcur, gspillc, buf1, spill,
                                              x, xb, xf8, W1, W2, W1b, W2b);
    build_ell<<<NBKT, 1024, 0, stream>>>(gcur, buf1, gspillc, spill, csr, cnt);

    // layer 1: gather fp8(x), self bf16(x) -> h1b + h1f8
    fused_layer<<<NN / 16, 512, 0, stream>>>(xb, xf8, cnt, csr, W1b, b1,
                                             nullptr, h1b, h1f8);
    // layer 2: gather fp8(h1), self bf16(h1) -> out
    fused_layer<<<NN / 16, 512, 0, stream>>>(h1b, (const unsigned int*)h1f8,
                                             cnt, csr, W2b, b2, out, nullptr, nullptr);
}